// Round 5
// baseline (141.432 us; speedup 1.0000x reference)
//
#include <hip/hip_runtime.h>

// VQ-VAE VectorQuantizer forward, MI355X (gfx950), fp32.
// N=32768 points x D=64 dims, K=1024 codes.
// Out: [0]=loss, [1..QE]=quantized [B,D,H,W], [+..]=indices [B,H*W] as f32.
//
// R5: K-split, barrier-free inner loop. 2048 blocks x 256 thr: each block =
// 128 pts x 128-code slice (LDS 69 KB -> 2 blocks/CU; staging overlaps the
// other block's compute; no chunk barriers). e/x tiles slot-swizzled so every
// ds_read_b128's 16 addresses tile all 8 bank-quads (R4's half-bank pattern
// doubled per-instr cost). Per-slice argmin -> packed (dist_bits<<32|idx) u64
// atomicMin (dist>0 so IEEE==integer order; tie -> lower idx; 0xAA poison
// acts as +inf). Kernel2 = R4's proven epilogue. Per-(point,code) rounding
// bit-identical to R1-R4 (absmax 0).

constexpr int D_    = 64;
constexpr int HW    = 1024;    // H*W
constexpr int PTS   = 128;     // points per block
constexpr int SLICE = 128;     // codes per slice
constexpr int SP    = 132;     // xT row stride (floats)
constexpr int SEC   = 132;     // eT row stride (floats)
constexpr int QE    = 2097152;
constexpr int IDX_OFF = 1 + QE;

__device__ __forceinline__ int swz(int s) {   // slot swizzle: pairs (2g,2g+1)
  int g = s >> 1, sw = (g >> 2) & 1;          // swap halves every 4 groups
  return (s & 1) ? (2 * g + 1 - sw) : (2 * g + sw);
}

__global__ __launch_bounds__(256, 2) void vq_dist_kernel(
    const float* __restrict__ in, const float* __restrict__ emb,
    unsigned long long* __restrict__ keys) {
  __shared__ float xT[D_ * SP];     // [d][swizzled point slot] 33.8 KB
  __shared__ float eT[D_ * SEC];    // [d][swizzled code slot]  33.8 KB
  __shared__ float e2c[SLICE];
  __shared__ float x2s[PTS];

  const int t     = threadIdx.x;
  const int kg    = t & 15;         // code group: 8 codes
  const int ptg   = t >> 4;         // point group: 8 points (16 groups)
  const int blk   = blockIdx.x;
  const int ptile = blk >> 3;       // 256 point tiles
  const int kb    = (blk & 7) * SLICE;
  const int b     = ptile >> 3;
  const int hw0   = (ptile & 7) * PTS;
  const float* inb = in + b * (D_ * HW) + hw0;

  // ---- stage x tile (coalesced float4 global; swizzled slot writes) ----
#pragma unroll
  for (int i = 0; i < 8; ++i) {
    int fi = t + i * 256;                 // 0..2047 float4s
    int d = fi >> 5, s = fi & 31;         // s = point slot
    float4 v = *(const float4*)(inb + d * HW + s * 4);
    *(float4*)(&xT[d * SP + 4 * swz(s)]) = v;
  }

  // ---- stage e transposed (code kl, dim-half h; swizzled column) ----
  {
    int kl = t >> 1, h = t & 1;
    int j = kl & 7;
    int col = 4 * swz((kl >> 3) * 2 + (j >> 2)) + (j & 3);
    const float4* ge = (const float4*)(emb + (kb + kl) * 64 + h * 32);
#pragma unroll
    for (int r = 0; r < 8; ++r) {
      float4 v = ge[r];
      int d = h * 32 + r * 4;
      eT[(d + 0) * SEC + col] = v.x;   // banks: col(kl) permutes 0..127 in
      eT[(d + 1) * SEC + col] = v.y;   // 8-blocks -> all 32 banks, 2-way max
      eT[(d + 2) * SEC + col] = v.z;
      eT[(d + 3) * SEC + col] = v.w;
    }
  }

  // ---- e2 for slice codes (expression identical to R1-R4: rounding!) ----
  if (t < SLICE) {
    const float4* e4 = (const float4*)(emb + (kb + t) * 64);
    float s = 0.f;
#pragma unroll
    for (int q = 0; q < 16; ++q) {
      float4 v = e4[q];
      s += v.x * v.x; s += v.y * v.y; s += v.z * v.z; s += v.w * v.w;
    }
    e2c[t] = s;
  }
  __syncthreads();

  // ---- x2[p] (sequential-d fmaf chain identical to R1-R4) ----
  if (t < PTS) {
    int j = t & 7;
    int cx = 4 * swz((t >> 3) * 2 + (j >> 2)) + (j & 3);
    float s = 0.f;
#pragma unroll 8
    for (int d = 0; d < D_; ++d) { float xv = xT[d * SP + cx]; s = fmaf(xv, xv, s); }
    x2s[t] = s;
  }
  __syncthreads();

  float x2r[8];
  {
    float4 xa = *(const float4*)&x2s[ptg * 8];
    float4 xb = *(const float4*)&x2s[ptg * 8 + 4];
    x2r[0]=xa.x; x2r[1]=xa.y; x2r[2]=xa.z; x2r[3]=xa.w;
    x2r[4]=xb.x; x2r[5]=xb.y; x2r[6]=xb.z; x2r[7]=xb.w;
  }

  // fragment offsets: swizzled slots -> each b128's addresses tile all 8 quads
  const int xo0 = 4 * swz(2 * ptg),     xo1 = 4 * swz(2 * ptg + 1);
  const int eo0 = 4 * swz(2 * kg),      eo1 = 4 * swz(2 * kg + 1);

  float acc[8][8];
#pragma unroll
  for (int i = 0; i < 8; ++i)
#pragma unroll
    for (int j = 0; j < 8; ++j) acc[i][j] = 0.f;

  // ---- barrier-free inner loop: 64 d, 4 b128 + 64 fmaf per d ----
#pragma unroll 4
  for (int d = 0; d < D_; ++d) {
    float4 xa = *(const float4*)&xT[d * SP + xo0];
    float4 xb = *(const float4*)&xT[d * SP + xo1];
    float4 e0 = *(const float4*)&eT[d * SEC + eo0];
    float4 e1 = *(const float4*)&eT[d * SEC + eo1];
    float xf[8] = {xa.x, xa.y, xa.z, xa.w, xb.x, xb.y, xb.z, xb.w};
    float ef[8] = {e0.x, e0.y, e0.z, e0.w, e1.x, e1.y, e1.z, e1.w};
#pragma unroll
    for (int i = 0; i < 8; ++i)
#pragma unroll
      for (int j = 0; j < 8; ++j)
        acc[i][j] = fmaf(xf[i], ef[j], acc[i][j]);
  }

  // ---- fold u = fl(fl(x2-2dot)+e2) (identical to R1-R4), per-point min ----
  float minv[8]; int mini[8];
#pragma unroll
  for (int i = 0; i < 8; ++i) { minv[i] = 3.4e38f; mini[i] = 0; }
  float e2f[8];
  {
    const float4* p4 = (const float4*)&e2c[kg * 8];
    float4 v0 = p4[0], v1 = p4[1];
    e2f[0]=v0.x; e2f[1]=v0.y; e2f[2]=v0.z; e2f[3]=v0.w;
    e2f[4]=v1.x; e2f[5]=v1.y; e2f[6]=v1.z; e2f[7]=v1.w;
  }
#pragma unroll
  for (int j = 0; j < 8; ++j) {
    int cg = kb + kg * 8 + j;            // ascending within thread
    float e2v = e2f[j];
#pragma unroll
    for (int i = 0; i < 8; ++i) {
      float u = fmaf(-2.f, acc[i][j], x2r[i]) + e2v;
      if (u < minv[i]) { minv[i] = u; mini[i] = cg; }   // strict <: first-min
    }
  }

  // ---- pack (dist_bits, idx) key; 16-lane min; one atomicMin per point ----
  // dist > 0 always (||x-e||^2 ~ 64) -> IEEE order == unsigned order; low 32
  // bits = index -> equal dist resolves to lower index (= ref first-argmin).
#pragma unroll
  for (int i = 0; i < 8; ++i) {
    unsigned long long key =
        (((unsigned long long)__float_as_uint(minv[i])) << 32) |
        (unsigned)mini[i];
#pragma unroll
    for (int off = 1; off < 16; off <<= 1) {
      unsigned long long ko = __shfl_xor(key, off);
      if (ko < key) key = ko;
    }
    if (kg == 0)
      atomicMin(&keys[ptile * PTS + ptg * 8 + i], key);  // poison 0xAA.. = +inf
  }
}

__global__ __launch_bounds__(256) void vq_epi_kernel(
    const float* __restrict__ in, const float* __restrict__ emb,
    const unsigned long long* __restrict__ keys, float* __restrict__ out,
    float* __restrict__ loss_acc, unsigned* __restrict__ cnt) {
  __shared__ float xT[D_ * SP];     // plain [d][p]; later holds ST values
  __shared__ int   idx_sel[PTS];
  __shared__ float redbuf[4];

  const int t   = threadIdx.x;
  const int blk = blockIdx.x;       // = ptile
  const int b   = blk >> 3;
  const int hw0 = (blk & 7) * PTS;
  const float* inb = in + b * (D_ * HW) + hw0;

#pragma unroll
  for (int i = 0; i < 8; ++i) {
    int fi = t + i * 256;
    int d = fi >> 5, p4 = fi & 31;
    *(float4*)(&xT[d * SP + p4 * 4]) = *(const float4*)(inb + d * HW + p4 * 4);
  }
  if (t < PTS) {
    int ix = (int)(unsigned)(keys[blk * PTS + t] & 0xFFFFFFFFull);
    idx_sel[t] = ix;
    out[IDX_OFF + blk * PTS + t] = (float)ix;   // coalesced
  }
  __syncthreads();

  // ---- gather codes, loss partial, overwrite xT with x + (q - x) ----
  float lp = 0.f;
#pragma unroll
  for (int i = 0; i < 8; ++i) {
    int fi = t + i * 256;                 // 0..2047
    int p = fi & 127, qd = fi >> 7;       // p contiguous per wave
    int cidx = idx_sel[p];
    float4 q = *(const float4*)(emb + cidx * 64 + qd * 4);
    float xv0 = xT[(qd * 4 + 0) * SP + p];
    float xv1 = xT[(qd * 4 + 1) * SP + p];
    float xv2 = xT[(qd * 4 + 2) * SP + p];
    float xv3 = xT[(qd * 4 + 3) * SP + p];
    float d0 = q.x - xv0, d1 = q.y - xv1, d2 = q.z - xv2, d3 = q.w - xv3;
    lp = fmaf(d0, d0, lp); lp = fmaf(d1, d1, lp);
    lp = fmaf(d2, d2, lp); lp = fmaf(d3, d3, lp);
    xT[(qd * 4 + 0) * SP + p] = xv0 + d0;
    xT[(qd * 4 + 1) * SP + p] = xv1 + d1;
    xT[(qd * 4 + 2) * SP + p] = xv2 + d2;
    xT[(qd * 4 + 3) * SP + p] = xv3 + d3;
  }

  // loss: wave -> block -> one device atomic; last block finalizes out[0]
#pragma unroll
  for (int off = 1; off < 64; off <<= 1) lp += __shfl_xor(lp, off);
  if ((t & 63) == 0) redbuf[t >> 6] = lp;
  __syncthreads();   // also orders xT rewrites before the stores below
  if (t == 0) {
    atomicAdd(loss_acc, redbuf[0] + redbuf[1] + redbuf[2] + redbuf[3]);
    __threadfence();
    unsigned old = atomicAdd(cnt, 1u);
    if (old == 255u) {
      __threadfence();
      float total = atomicAdd(loss_acc, 0.0f);  // coherent read-back
      float m = total * (1.0f / 2097152.0f);
      out[0] = m + 0.25f * m;                   // ref op order
    }
  }

  // quantized output [B,D,H,W]: scalar coalesced stores (out+1 is 4B-aligned)
  float* outq = out + 1 + b * (D_ * HW) + hw0;
#pragma unroll
  for (int i = 0; i < 32; ++i) {
    int oi = t + i * 256;                 // 0..8191
    int d = oi >> 7, p = oi & 127;
    outq[d * HW + p] = xT[d * SP + p];
  }
}

extern "C" void kernel_launch(void* const* d_in, const int* in_sizes, int n_in,
                              void* d_out, int out_size, void* d_ws, size_t ws_size,
                              hipStream_t stream) {
  const float* in  = (const float*)d_in[0];
  const float* emb = (const float*)d_in[1];
  float* out = (float*)d_out;
  float* loss_acc = (float*)d_ws;                                   // ws[0]
  unsigned* cnt   = (unsigned*)d_ws + 4;                            // ws[16B]
  unsigned long long* keys =
      (unsigned long long*)((char*)d_ws + 1024);                    // 256 KB

  hipMemsetAsync(d_ws, 0, 64, stream);   // zero loss accumulator + counter
  // keys need NO init: 0xAA poison > any real key (dist>0 -> top bit 0)
  vq_dist_kernel<<<2048, 256, 0, stream>>>(in, emb, keys);
  vq_epi_kernel<<<256, 256, 0, stream>>>(in, emb, keys, out, loss_acc, cnt);
}